// Round 4
// baseline (173.508 us; speedup 1.0000x reference)
//
#include <hip/hip_runtime.h>

typedef __attribute__((ext_vector_type(8))) short short8;
typedef __attribute__((ext_vector_type(4))) float floatx4;

#define B_   16
#define S_   4096
#define D_   128
#define P_   4096
#define CTOT 496                 // 16+32+64+128+256
#define BP   (B_ * CTOT)
#define WPADG 512                // padded wave count for decoder K
#define CENC 1488                // total encoder columns (sum 3n)
#define INV2PI 0.15915494309189535f

// round-to-nearest-even float -> bf16
__device__ __forceinline__ unsigned short f2bf(float f) {
    unsigned u = __float_as_uint(f);
    u += 0x7fffu + ((u >> 16) & 1u);
    return (unsigned short)(u >> 16);
}
__device__ __forceinline__ unsigned int pack2(float a, float b) {
    return (unsigned int)f2bf(a) | ((unsigned int)f2bf(b) << 16);
}

// ---------------------------------------------------------------------------
// pack_all: kv fp32 -> bf16 (linear), W_enc -> wencb[c][d] bf16,
// W_dec -> wdbT[d][w] bf16 (w padded to 512), zero accb. One dispatch.
// ---------------------------------------------------------------------------
#define NKVB 4096                // kv blocks: 4096*256 threads * 8 elem
#define NWB  1000                // weight blocks: 256000 shorts
#define NZB  93                  // zero blocks for accb (23808 floats)
__global__ void pack_all(const float* __restrict__ kv,
                         const float* __restrict__ we0, const float* __restrict__ we1,
                         const float* __restrict__ we2, const float* __restrict__ we3,
                         const float* __restrict__ we4,
                         const float* __restrict__ wd0, const float* __restrict__ wd1,
                         const float* __restrict__ wd2, const float* __restrict__ wd3,
                         const float* __restrict__ wd4,
                         unsigned short* __restrict__ kvb16,
                         unsigned short* __restrict__ wencb,
                         unsigned short* __restrict__ wdbT,
                         float* __restrict__ accb)
{
    const int bid = blockIdx.x, tid = threadIdx.x;
    if (bid < NKVB) {
        size_t base = ((size_t)bid * 256 + tid) * 8;
        float4 a = *(const float4*)(kv + base);
        float4 c = *(const float4*)(kv + base + 4);
        union { unsigned int u[4]; short8 s; } r;
        r.u[0] = pack2(a.x, a.y); r.u[1] = pack2(a.z, a.w);
        r.u[2] = pack2(c.x, c.y); r.u[3] = pack2(c.z, c.w);
        *(short8*)(kvb16 + base) = r.s;
    } else if (bid < NKVB + NWB) {
        int idx = (bid - NKVB) * 256 + tid;
        const int NE = CENC * D_;                 // 190464
        if (idx < NE) {
            int c = idx >> 7, d = idx & 127;
            const float* src; int off;
            if (c < 48)        { src = we0; off = 0;   }
            else if (c < 144)  { src = we1; off = 48;  }
            else if (c < 336)  { src = we2; off = 144; }
            else               { src = (c < 720) ? we3 : we4; off = (c < 720) ? 336 : 720; }
            wencb[idx] = f2bf(src[(size_t)(c - off) * D_ + d]);
        } else {
            int k = idx - NE;                      // < 65536
            int d = k >> 9, w = k & 511;
            float v = 0.0f;
            if (w < CTOT) {
                const float* src; int off, nl;
                if (w < 16)       { src = wd0; off = 0;   nl = 16;  }
                else if (w < 48)  { src = wd1; off = 16;  nl = 32;  }
                else if (w < 112) { src = wd2; off = 48;  nl = 64;  }
                else if (w < 240) { src = wd3; off = 112; nl = 128; }
                else              { src = wd4; off = 240; nl = 256; }
                v = src[(size_t)d * nl + (w - off)];
            }
            wdbT[k] = f2bf(v);
        }
    } else {
        int idx = (bid - NKVB - NWB) * 256 + tid;
        if (idx < 3 * BP) accb[idx] = 0.0f;
    }
}

// ---------------------------------------------------------------------------
// Encoder: no LDS, no barriers — each wave is an independent job group.
// Per b: 288 waves; wave -> (t-tile bx, stride widx/nw over bx's chunk list).
// Waves/bx: {24,12,6,2} for chunk counts {93,45,21,9} (~4 chunks/wave).
// A-frags (64t x 128d bf16 tile) loaded once from global into VGPRs,
// reused across chunks. B-frag = 16B global load/kstep. C layout (verified):
// col = lane&15 = c, row = quad*4+reg = t.
// ---------------------------------------------------------------------------
__global__ __launch_bounds__(256) void encoder(
    const unsigned short* __restrict__ kvb16, const int* __restrict__ positions,
    const unsigned short* __restrict__ wencb,
    const float* __restrict__ bfr0, const float* __restrict__ bfr1,
    const float* __restrict__ bfr2, const float* __restrict__ bfr3,
    const float* __restrict__ bfr4,
    float* __restrict__ accb)
{
    const int b    = blockIdx.y;
    const int gw   = blockIdx.x * 4 + (threadIdx.x >> 6);   // 0..287
    const int lane = threadIdx.x & 63, ln15 = lane & 15, quad = lane >> 4;

    int bx, widx, nw;
    if (gw < 96)       { bx = gw / 24;                widx = gw % 24;      nw = 24; }
    else if (gw < 144) { int r = gw - 96;  bx = 4 + r / 12;  widx = r % 12; nw = 12; }
    else if (gw < 192) { int r = gw - 144; bx = 8 + r / 6;   widx = r % 6;  nw = 6;  }
    else               { int r = gw - 192; bx = 16 + r / 2;  widx = r % 2;  nw = 2;  }
    const int t0  = S_ - 64 * (bx + 1);
    const int sz2 = (bx < 16) ? 12 : 0, sz3 = (bx < 8) ? 24 : 0;
    const int cnt = 9 + sz2 + sz3 + ((bx < 4) ? 48 : 0);

    // A-frags: 16 x 16B direct global loads (L1/L2 resident)
    const unsigned short* abase = kvb16 + ((size_t)(b * S_ + t0 + ln15)) * D_ + quad * 8;
    short8 afr[4][4];
    #pragma unroll
    for (int m = 0; m < 4; ++m)
        #pragma unroll
        for (int k = 0; k < 4; ++k)
            afr[m][k] = *(const short8*)(abase + (m * 16) * D_ + k * 32);

    // per-lane position factors for the 16 (m,r) rows this lane owns
    float pfr[16];
    #pragma unroll
    for (int m = 0; m < 4; ++m) {
        int4 pi = *(const int4*)(positions + t0 + m * 16 + quad * 4);
        pfr[m * 4 + 0] = (float)pi.x * (1.0f / 8192.0f);
        pfr[m * 4 + 1] = (float)pi.y * (1.0f / 8192.0f);
        pfr[m * 4 + 2] = (float)pi.z * (1.0f / 8192.0f);
        pfr[m * 4 + 3] = (float)pi.w * (1.0f / 8192.0f);
    }

    const int   n_l[5]  = {16, 32, 64, 128, 256};
    const int   coff[5] = {0, 16, 48, 112, 240};
    const int   c3[5]   = {0, 48, 144, 336, 720};
    const float al[5]   = {0.001f, 0.005f, 0.02f, 0.05f, 0.1f};
    const float l2m[5]  = {-0.0014434169f, -0.0072315692f, -0.0291463449f,
                           -0.0740005794f, -0.1520030934f};
    const float* bfp[5] = {bfr0, bfr1, bfr2, bfr3, bfr4};

    int   lprev = -1;
    float wtr[16];

    for (int ch = widx; ch < cnt; ch += nw) {
        // decode (level, ci) from chunk index within this bx's list
        int c = ch, l = 0;
        if (c >= 3) { c -= 3; l = 1;
            if (c >= 6) { c -= 6; l = 2;
                if (c >= sz2) { c -= sz2; l = 3;
                    if (c >= sz3) { c -= sz3; l = 4; } } } }
        const int ci = c, n = n_l[l];

        if (l != lprev) {
            lprev = l;
            const float s1 = (float)(S_ - 1 - t0);
            #pragma unroll
            for (int i = 0; i < 16; ++i) {
                float trel = (float)((i >> 2) * 16 + quad * 4 + (i & 3));
                wtr[i] = al[l] * exp2f((s1 - trel) * l2m[l]);
            }
        }

        const unsigned short* wrow = wencb + (size_t)(c3[l] + ci * 16 + ln15) * D_ + quad * 8;
        floatx4 acc[4];
        #pragma unroll
        for (int m = 0; m < 4; ++m) acc[m] = (floatx4){0.f, 0.f, 0.f, 0.f};
        #pragma unroll
        for (int k = 0; k < 4; ++k) {
            short8 bfg = *(const short8*)(wrow + k * 32);
            #pragma unroll
            for (int m = 0; m < 4; ++m)
                acc[m] = __builtin_amdgcn_mfma_f32_16x16x32_bf16(afr[m][k], bfg, acc[m], 0, 0, 0);
        }

        const int kind  = (ci * 16) / n;          // chunk lies in one kind
        const int local = ci * 16 + ln15 - kind * n;
        const float bsv = (kind == 0) ? bfp[l][local] : 0.0f;
        float s = 0.0f;
        #pragma unroll
        for (int m = 0; m < 4; ++m)
            #pragma unroll
            for (int r = 0; r < 4; ++r) {
                float v = acc[m][r];
                if (kind == 0) {
                    float rev = bsv * pfr[m * 4 + r];   // sin(2pi*base*pos/8192)
                    rev -= floorf(rev);
                    v *= __builtin_amdgcn_sinf(rev);
                } else if (kind == 1) {
                    v = fabsf(v);
                }
                s += wtr[m * 4 + r] * v;
            }
        s += __shfl_xor(s, 16);
        s += __shfl_xor(s, 32);
        if (lane < 16)
            atomicAdd(accb + (size_t)kind * BP + b * CTOT + coff[l] + local, s);
    }
}

// ---------------------------------------------------------------------------
// Decoder (combine folded): per block compute Q/A/P params from accb in regs,
// then out[b,p,:] = sum_w A*sin(2pi*rev) * wd[w,:] via bf16 MFMA.
// Block 64p x 128d; K=512 in 2 passes of 256 -> v[64][264] bf16 (34 KB LDS).
// ---------------------------------------------------------------------------
__global__ __launch_bounds__(256) void decoder(
    const float* __restrict__ accb,
    const float* __restrict__ b0, const float* __restrict__ b1,
    const float* __restrict__ b2, const float* __restrict__ b3,
    const float* __restrict__ b4,
    const unsigned short* __restrict__ wdbT, const int* __restrict__ rpos,
    float* __restrict__ out)
{
    __shared__ unsigned short v[64 * 264];
    __shared__ float rpn[64];
    const int b = blockIdx.y, p0 = blockIdx.x * 64, tid = threadIdx.x;
    if (tid < 64) rpn[tid] = (float)rpos[p0 + tid] * (1.0f / 8192.0f);

    // combine: this thread's column params for both halves (w = h*256 + tid)
    float Qv[2], Av[2], Pv[2];
    #pragma unroll
    for (int h = 0; h < 2; ++h) {
        int w = h * 256 + tid;
        float A = 0.f, Q = 0.f, P = 0.f;
        if (w < CTOT) {
            const float* bf; int off;
            if (w < 16)       { bf = b0; off = 0;   }
            else if (w < 48)  { bf = b1; off = 16;  }
            else if (w < 112) { bf = b2; off = 48;  }
            else if (w < 240) { bf = b3; off = 112; }
            else              { bf = b4; off = 240; }
            float f  = accb[0 * BP + b * CTOT + w];
            A        = accb[1 * BP + b * CTOT + w];
            float ph = accb[2 * BP + b * CTOT + w];
            Q = f + bf[w - off];
            P = ph * INV2PI;
        }
        Qv[h] = Q; Av[h] = A; Pv[h] = P;
    }

    const int wid = tid >> 6, lane = tid & 63, ln = lane & 15, quad = lane >> 4;
    const int nt0 = wid * 2;

    floatx4 acc[4][2];
    #pragma unroll
    for (int m = 0; m < 4; ++m)
        #pragma unroll
        for (int j = 0; j < 2; ++j) acc[m][j] = (floatx4){0.f, 0.f, 0.f, 0.f};

    #pragma unroll
    for (int half = 0; half < 2; ++half) {
        const int w0 = half * 256;
        const float Q = Qv[half], A = Av[half], Ph = Pv[half];
        __syncthreads();   // prior MFMA reads done (and rpn ready on pass 0)
        for (int p = 0; p < 64; ++p) {
            float r = fmaf(Q, rpn[p], Ph);
            r -= floorf(r);
            v[p * 264 + tid] = f2bf(A * __builtin_amdgcn_sinf(r));
        }
        __syncthreads();

        #pragma unroll
        for (int kk = 0; kk < 8; ++kk) {
            short8 bn[2];
            #pragma unroll
            for (int j = 0; j < 2; ++j)
                bn[j] = *(const short8*)(wdbT + (size_t)((nt0 + j) * 16 + ln) * WPADG
                                         + w0 + kk * 32 + quad * 8);
            short8 am[4];
            #pragma unroll
            for (int m = 0; m < 4; ++m)
                am[m] = *(const short8*)&v[(m * 16 + ln) * 264 + kk * 32 + quad * 8];
            #pragma unroll
            for (int m = 0; m < 4; ++m)
                #pragma unroll
                for (int j = 0; j < 2; ++j)
                    acc[m][j] = __builtin_amdgcn_mfma_f32_16x16x32_bf16(
                                    am[m], bn[j], acc[m][j], 0, 0, 0);
        }
    }

    // store: col = lane&15 -> d, row = quad*4+reg -> p
    #pragma unroll
    for (int m = 0; m < 4; ++m)
        #pragma unroll
        for (int j = 0; j < 2; ++j)
            #pragma unroll
            for (int r = 0; r < 4; ++r) {
                int p = p0 + m * 16 + quad * 4 + r;
                int d = (nt0 + j) * 16 + ln;
                out[((size_t)(b * P_ + p)) * D_ + d] = acc[m][j][r];
            }
}

// ---------------------------------------------------------------------------
extern "C" void kernel_launch(void* const* d_in, const int* in_sizes, int n_in,
                              void* d_out, int out_size, void* d_ws, size_t ws_size,
                              hipStream_t stream)
{
    const float* kv        = (const float*)d_in[0];
    const int*   positions = (const int*)d_in[1];
    const int*   rpos      = (const int*)d_in[2];

    char* ws = (char*)d_ws;
    float*          accb  = (float*)(ws + 0);                 // 95232 B
    unsigned short* wencb = (unsigned short*)(ws + 95232);    // 380928 B
    unsigned short* wdbT  = (unsigned short*)(ws + 476160);   // 131072 B
    unsigned short* kvb16 = (unsigned short*)(ws + 607232);   // 16777216 B

    pack_all<<<NKVB + NWB + NZB, 256, 0, stream>>>(
        kv,
        (const float*)d_in[3], (const float*)d_in[6], (const float*)d_in[9],
        (const float*)d_in[12], (const float*)d_in[15],
        (const float*)d_in[4], (const float*)d_in[7], (const float*)d_in[10],
        (const float*)d_in[13], (const float*)d_in[16],
        kvb16, wencb, wdbT, accb);

    encoder<<<dim3(72, B_), 256, 0, stream>>>(
        kvb16, positions, wencb,
        (const float*)d_in[5], (const float*)d_in[8], (const float*)d_in[11],
        (const float*)d_in[14], (const float*)d_in[17],
        accb);

    decoder<<<dim3(P_ / 64, B_), 256, 0, stream>>>(
        accb,
        (const float*)d_in[5], (const float*)d_in[8], (const float*)d_in[11],
        (const float*)d_in[14], (const float*)d_in[17],
        wdbT, rpos, (float*)d_out);
}